// Round 8
// baseline (677.241 us; speedup 1.0000x reference)
//
#include <hip/hip_runtime.h>
#include <cstddef>

#define NNODES 16384
#define DMODEL 256
#define CCH 64
#define SQLEN 1024
#define NGRAPH 16
#define ADH 128

typedef __bf16 bf16;
typedef __attribute__((ext_vector_type(8))) __bf16 bf16x8;
typedef __attribute__((ext_vector_type(4))) __bf16 bf16x4;
typedef __attribute__((ext_vector_type(4))) float floatx4;

// ======================= bf16 MFMA GEMM: C[M,N] = A[M,K] @ Bt[N,K]^T =======================
// BM=128, BK=64 (XOR-swizzled LDS), BN=128 (wave 64x64) or BN=64 (wave 32x64).
template <int BN>
__global__ __launch_bounds__(256) void mfma_gemm_t(
    const bf16* __restrict__ A, const bf16* __restrict__ Bt,
    const float* __restrict__ bias, float* __restrict__ Cf, bf16* __restrict__ Cb,
    int M, int N, int K, int act,
    const float* __restrict__ gas, const float* __restrict__ gad,
    float* __restrict__ ssrc, float* __restrict__ sdst)
{
  constexpr int BM = 128;
  constexpr int MW = (BN == 128) ? 4 : 2;
  constexpr int NW = 4;
  constexpr int ACH = BM / 8;
  constexpr int TCH = (BM + BN) / 8;
  __shared__ bf16 As[BM * 64];
  __shared__ bf16 Bs[BN * 64];
  const int tid = threadIdx.x;
  const int wave = tid >> 6, lane = tid & 63;
  const int m0 = blockIdx.y * BM, n0 = blockIdx.x * BN;
  const int lr = lane & 15, quad = lane >> 4;
  const int wm = (BN == 128) ? (wave >> 1) * 64 : wave * 32;
  const int wn = (BN == 128) ? (wave & 1) * 64 : 0;
  const int r8 = lane >> 3, cu = lane & 7;
  const int scol = (cu ^ r8) * 8;

  floatx4 acc[MW][NW];
  const floatx4 zero = {0.f, 0.f, 0.f, 0.f};
#pragma unroll
  for (int i = 0; i < MW; i++)
#pragma unroll
    for (int j = 0; j < NW; j++) acc[i][j] = zero;

  for (int k0 = 0; k0 < K; k0 += 64) {
#pragma unroll
    for (int c = wave; c < TCH; c += 4) {
      const bf16* g;
      bf16* l;
      if (c < ACH) {
        g = A + (size_t)(m0 + c * 8 + r8) * K + k0 + scol;
        l = &As[c * 512];
      } else {
        int c2 = c - ACH;
        g = Bt + (size_t)(n0 + c2 * 8 + r8) * K + k0 + scol;
        l = &Bs[c2 * 512];
      }
      __builtin_amdgcn_global_load_lds(
          (const __attribute__((address_space(1))) void*)g,
          (__attribute__((address_space(3))) void*)l, 16, 0, 0);
    }
    __syncthreads();
#pragma unroll
    for (int ks = 0; ks < 2; ks++) {
      bf16x8 af[MW], bfr[NW];
#pragma unroll
      for (int i = 0; i < MW; i++) {
        int row = wm + i * 16 + lr;
        af[i] = *(const bf16x8*)&As[(row * 8 + ((ks * 4 + quad) ^ (row & 7))) * 8];
      }
#pragma unroll
      for (int i = 0; i < NW; i++) {
        int row = wn + i * 16 + lr;
        bfr[i] = *(const bf16x8*)&Bs[(row * 8 + ((ks * 4 + quad) ^ (row & 7))) * 8];
      }
#pragma unroll
      for (int mi = 0; mi < MW; mi++)
#pragma unroll
        for (int ni = 0; ni < NW; ni++)
          acc[mi][ni] = __builtin_amdgcn_mfma_f32_16x16x32_bf16(af[mi], bfr[ni], acc[mi][ni], 0, 0, 0);
    }
    __syncthreads();
  }

  float as_v[4], ad_v[4];
  int head = 0;
  if (gas) {
    head = (n0 + wn) >> 6;
#pragma unroll
    for (int ni = 0; ni < 4; ni++) {
      as_v[ni] = gas[head * 64 + ni * 16 + lr];
      ad_v[ni] = gad[head * 64 + ni * 16 + lr];
    }
  }

#pragma unroll
  for (int mi = 0; mi < MW; mi++) {
    int rbase = m0 + wm + mi * 16 + quad * 4;
#pragma unroll
    for (int r = 0; r < 4; r++) {
      int row = rbase + r;
      float s1 = 0.f, s2 = 0.f;
#pragma unroll
      for (int ni = 0; ni < NW; ni++) {
        int col = n0 + wn + ni * 16 + lr;
        float v = acc[mi][ni][r];
        if (gas) { s1 += v * as_v[ni]; s2 += v * ad_v[ni]; }
        if (bias) v += bias[col];
        if (act == 1) v = fmaxf(v, 0.f);
        if (Cf) Cf[(size_t)row * N + col] = v;
        if (Cb) Cb[(size_t)row * N + col] = (bf16)v;
      }
      if (gas) {
        s1 += __shfl_xor(s1, 1); s1 += __shfl_xor(s1, 2);
        s1 += __shfl_xor(s1, 4); s1 += __shfl_xor(s1, 8);
        s2 += __shfl_xor(s2, 1); s2 += __shfl_xor(s2, 2);
        s2 += __shfl_xor(s2, 4); s2 += __shfl_xor(s2, 8);
        if (lr == 0) {
          ssrc[row * 4 + head] = s1;
          sdst[row * 4 + head] = s2;
        }
      }
    }
  }
}

// ======================= weight transpose+convert =======================
struct W11 { const float* s[11]; bf16* d[11]; };

__global__ __launch_bounds__(256) void transpose11_kernel(W11 wl)
{
  __shared__ float t[32][33];
  const float* W = wl.s[blockIdx.z];
  bf16* Wt = wl.d[blockIdx.z];
  int n0 = blockIdx.x * 32, k0 = blockIdx.y * 32;
  int tx = threadIdx.x & 31, ty = threadIdx.x >> 5;
#pragma unroll
  for (int i = 0; i < 4; i++) t[ty + 8 * i][tx] = W[(size_t)(k0 + ty + 8 * i) * 256 + n0 + tx];
  __syncthreads();
#pragma unroll
  for (int i = 0; i < 4; i++) Wt[(size_t)(n0 + ty + 8 * i) * 256 + k0 + tx] = (bf16)t[tx][ty + 8 * i];
}

__global__ __launch_bounds__(256) void transpose_kernel(const float* __restrict__ W, bf16* __restrict__ Wt,
                                                        int K, int N)
{
  __shared__ float t[32][33];
  int n0 = blockIdx.x * 32, k0 = blockIdx.y * 32;
  int tx = threadIdx.x & 31, ty = threadIdx.x >> 5;
#pragma unroll
  for (int i = 0; i < 4; i++) t[ty + 8 * i][tx] = W[(size_t)(k0 + ty + 8 * i) * N + n0 + tx];
  __syncthreads();
#pragma unroll
  for (int i = 0; i < 4; i++) Wt[(size_t)(n0 + ty + 8 * i) * K + k0 + tx] = (bf16)t[tx][ty + 8 * i];
}

// ======================= V transpose =======================
__global__ __launch_bounds__(256) void vtrans_kernel(const bf16* __restrict__ V, int ldv, int coff,
                                                     bf16* __restrict__ Vt)
{
  __shared__ bf16 t[32][34];
  int b = blockIdx.z;
  int head = blockIdx.y >> 2, d0 = (blockIdx.y & 3) * 32;
  int k0 = blockIdx.x * 32;
  int tx = threadIdx.x & 31, ty = threadIdx.x >> 5;
#pragma unroll
  for (int i = 0; i < 4; i++)
    t[ty + 8 * i][tx] = V[((size_t)(b * SQLEN + k0 + ty + 8 * i)) * ldv + coff + head * ADH + d0 + tx];
  __syncthreads();
#pragma unroll
  for (int i = 0; i < 4; i++)
    Vt[((size_t)((b * 2 + head) * ADH) + d0 + ty + 8 * i) * SQLEN + k0 + tx] = t[tx][ty + 8 * i];
}

// ======================= MFMA flash attention — S^T operand order =======================
// S^T = K·Q^T via mfma(kf, qf): D lane = query, rows = keys. Enables packed b64 P-stores
// (4 consecutive keys per reg-quad) and a single per-lane softmax denominator.
// Static-max softmax (scores tiny; scale*log2e prefolded into Q fragments).
// grid: (SQLEN/64, 2, NGRAPH) = 512 blocks.
__global__ __launch_bounds__(256) void attn_mfma_kernel(
    const bf16* __restrict__ Q, int ldq, const bf16* __restrict__ K, int ldk,
    const bf16* __restrict__ Vt, bf16* __restrict__ O)
{
  const int qt = blockIdx.x, head = blockIdx.y, b = blockIdx.z;
  const int tid = threadIdx.x, wave = tid >> 6, lane = tid & 63;
  const int lr = lane & 15, quad = lane >> 4;

  __shared__ __align__(16) bf16 Ks[2][64 * 128];   // [key][d], 16B-unit XOR swizzle
  __shared__ __align__(16) bf16 Vts[2][128 * 64];  // [d][key], swizzled
  __shared__ __align__(16) bf16 Ps[4][16][72];     // per-wave P: [q][key], padded

  const int q0 = qt * 64 + wave * 16;
  const size_t qrow = ((size_t)b * SQLEN + q0 + lr) * ldq + head * ADH;
  const float scale2 = 0.08838834764831845f * 1.4426950408889634f;  // log2e/sqrt(128)
  bf16x8 qf[4];
#pragma unroll
  for (int s = 0; s < 4; s++) {
    qf[s] = *(const bf16x8*)&Q[qrow + s * 32 + quad * 8];
#pragma unroll
    for (int j = 0; j < 8; j++) qf[s][j] = (bf16)((float)qf[s][j] * scale2);
  }

  floatx4 accO[8];
  const floatx4 zero = {0.f, 0.f, 0.f, 0.f};
#pragma unroll
  for (int n = 0; n < 8; n++) accO[n] = zero;
  float lsum = 0.f;  // per-lane (lane = query, quad = key-subset) partial denominator

  const bf16* kbase = K + ((size_t)b * SQLEN) * ldk + head * ADH;
  const bf16* vtb = Vt + ((size_t)((b * 2 + head) * ADH)) * SQLEN;

  auto stage = [&](int buf, int k0) {
#pragma unroll
    for (int p = 0; p < 4; p++) {
      int bu = p * 256 + wave * 64;
      int u = bu + lane;
      int r = u >> 4, cq = u & 15;
      int c = cq ^ (r & 7);
      __builtin_amdgcn_global_load_lds(
          (const __attribute__((address_space(1))) void*)(kbase + (size_t)(k0 + r) * ldk + c * 8),
          (__attribute__((address_space(3))) void*)&Ks[buf][bu * 8], 16, 0, 0);
    }
#pragma unroll
    for (int p = 0; p < 4; p++) {
      int bu = p * 256 + wave * 64;
      int u = bu + lane;
      int r = u >> 3, cq = u & 7;
      int c = cq ^ (r & 7);
      __builtin_amdgcn_global_load_lds(
          (const __attribute__((address_space(1))) void*)(vtb + (size_t)r * SQLEN + k0 + c * 8),
          (__attribute__((address_space(3))) void*)&Vts[buf][bu * 8], 16, 0, 0);
    }
  };

  stage(0, 0);
  for (int it = 0; it < 16; it++) {
    __syncthreads();
    if (it < 15) stage((it + 1) & 1, (it + 1) * 64);
    const bf16* ks = Ks[it & 1];
    const bf16* vs = Vts[it & 1];

    // S^T[key][q]: A = K-frag (lane = key), B = Q-frag (lane = query)
    floatx4 accS[4];
#pragma unroll
    for (int i = 0; i < 4; i++) accS[i] = zero;
#pragma unroll
    for (int i = 0; i < 4; i++) {
#pragma unroll
      for (int s = 0; s < 4; s++) {
        int r = i * 16 + lr;
        int cpr = (s * 4 + quad) ^ (r & 7);
        bf16x8 kf = *(const bf16x8*)&ks[(r * 16 + cpr) * 8];
        accS[i] = __builtin_amdgcn_mfma_f32_16x16x32_bf16(kf, qf[s], accS[i], 0, 0, 0);
      }
    }

    // p = exp2(S'): lane q=lr holds keys i*16 + quad*4 + r -> packed b64 stores
#pragma unroll
    for (int i = 0; i < 4; i++) {
      bf16x4 pk;
#pragma unroll
      for (int r = 0; r < 4; r++) {
        float p = exp2f(accS[i][r]);
        pk[r] = (bf16)p;
        lsum += p;
      }
      *(bf16x4*)&Ps[wave][lr][i * 16 + quad * 4] = pk;
    }

    bf16x8 pf[2];
#pragma unroll
    for (int s = 0; s < 2; s++) pf[s] = *(const bf16x8*)&Ps[wave][lr][s * 32 + quad * 8];
#pragma unroll
    for (int n = 0; n < 8; n++) {
#pragma unroll
      for (int s = 0; s < 2; s++) {
        int r = n * 16 + lr;
        int cpr = (s * 4 + quad) ^ (r & 7);
        bf16x8 vf = *(const bf16x8*)&vs[(r * 8 + cpr) * 8];
        accO[n] = __builtin_amdgcn_mfma_f32_16x16x32_bf16(pf[s], vf, accO[n], 0, 0, 0);
      }
    }
  }

  // denominator: lanes with same q (across quads) hold disjoint key subsets
  lsum += __shfl_xor(lsum, 16);
  lsum += __shfl_xor(lsum, 32);
  float linv[4];
#pragma unroll
  for (int r = 0; r < 4; r++) linv[r] = 1.f / __shfl(lsum, quad * 4 + r);
  size_t obase = ((size_t)b * SQLEN + q0 + quad * 4) * DMODEL + head * ADH;
#pragma unroll
  for (int n = 0; n < 8; n++)
#pragma unroll
    for (int r = 0; r < 4; r++)
      O[obase + (size_t)r * DMODEL + n * 16 + lr] = (bf16)(accO[n][r] * linv[r]);
}

// ======================= fc1 =======================
__global__ __launch_bounds__(256) void fc1_kernel(
    const float* __restrict__ x, const float* __restrict__ W,
    const float* __restrict__ b, bf16* __restrict__ h0)
{
  int idx = blockIdx.x * 256 + threadIdx.x;
  int n = idx >> 6, j = idx & 63;
  const float* xr = x + (size_t)n * 16;
  float s = b[j];
#pragma unroll
  for (int k = 0; k < 16; k++) s += xr[k] * W[k * 64 + j];
  h0[idx] = (bf16)s;
}

// ======================= CSR build =======================
__global__ __launch_bounds__(256) void hist_kernel(const int* __restrict__ dst, int* __restrict__ cnt, int E)
{
  int e = blockIdx.x * 256 + threadIdx.x;
  if (e < E) atomicAdd(&cnt[dst[e]], 1);
}

__global__ __launch_bounds__(256) void scan_kernel(const int* __restrict__ cnt, int* __restrict__ offs,
                                                   int* __restrict__ cur, int n)
{
  __shared__ int partial[256];
  int tid = threadIdx.x;
  int chunk = n / 256;
  int base = tid * chunk;
  int s = 0;
  for (int i = 0; i < chunk; i++) s += cnt[base + i];
  partial[tid] = s;
  __syncthreads();
  for (int off = 1; off < 256; off <<= 1) {
    int v = 0;
    if (tid >= off) v = partial[tid - off];
    __syncthreads();
    partial[tid] += v;
    __syncthreads();
  }
  int run = partial[tid] - s;
  for (int i = 0; i < chunk; i++) {
    offs[base + i] = run;
    cur[base + i] = run;
    run += cnt[base + i];
  }
  if (tid == 255) offs[n] = run;
}

__global__ __launch_bounds__(256) void scatter_kernel(const int* __restrict__ src, const int* __restrict__ dst,
                                                      int* __restrict__ cur, int* __restrict__ csr, int E)
{
  int e = blockIdx.x * 256 + threadIdx.x;
  if (e < E) {
    int p = atomicAdd(&cur[dst[e]], 1);
    csr[p] = src[e];
  }
}

// ======================= fused GAT softmax + aggregation (one wave per node) =======================
__global__ __launch_bounds__(256) void gat_fused_kernel(
    const bf16* __restrict__ hW, const int* __restrict__ offs, const int* __restrict__ csr,
    const float* __restrict__ ssrc, const float* __restrict__ sdst,
    const float* __restrict__ bias, float* __restrict__ out, bf16* __restrict__ outb)
{
  __shared__ float pL[4][128][4];
  int wave = threadIdx.x >> 6, lane = threadIdx.x & 63;
  int n = blockIdx.x * 4 + wave;
  int row0 = offs[n], row1 = offs[n + 1];
  int deg = row1 - row0;

  int src_reg = (lane < deg) ? csr[row0 + lane] : 0;

  int h1 = lane & 3, el = lane >> 2;
  float sd = sdst[n * 4 + h1];
  float m = -1e30f;
  for (int e = el; e < deg; e += 16) {
    int src = (e < 64) ? __shfl(src_reg, e) : csr[row0 + e];
    float sc = ssrc[src * 4 + h1] + sd;
    sc = (sc > 0.f) ? sc : 0.2f * sc;
    if (e < 128) pL[wave][e][h1] = sc;
    m = fmaxf(m, sc);
  }
  m = fmaxf(m, __shfl_xor(m, 4));
  m = fmaxf(m, __shfl_xor(m, 8));
  m = fmaxf(m, __shfl_xor(m, 16));
  m = fmaxf(m, __shfl_xor(m, 32));
  float den = 0.f;
  for (int e = el; e < deg; e += 16) {
    float sc;
    if (e < 128) sc = pL[wave][e][h1];
    else {
      int src = csr[row0 + e];
      sc = ssrc[src * 4 + h1] + sd;
      sc = (sc > 0.f) ? sc : 0.2f * sc;
    }
    float p = __expf(sc - m);
    if (e < 128) pL[wave][e][h1] = p;
    den += p;
  }
  den += __shfl_xor(den, 4);
  den += __shfl_xor(den, 8);
  den += __shfl_xor(den, 16);
  den += __shfl_xor(den, 32);
  float rd1 = 1.f / (den + 1e-16f);

  int h2 = lane >> 4;
  float rd = __shfl(rd1, h2);
  float m2 = __shfl(m, h2);
  float sd2 = __shfl(sd, h2);
  float4 acc = {0.f, 0.f, 0.f, 0.f};
  for (int i = 0; i < deg; i++) {
    int src = (i < 64) ? __shfl(src_reg, i) : csr[row0 + i];
    float p;
    if (i < 128) p = pL[wave][i][h2];
    else {
      float sc = ssrc[src * 4 + h2] + sd2;
      sc = (sc > 0.f) ? sc : 0.2f * sc;
      p = __expf(sc - m2);
    }
    bf16x4 hv = *(const bf16x4*)&hW[(size_t)src * DMODEL + lane * 4];
    acc.x += p * (float)hv.x; acc.y += p * (float)hv.y;
    acc.z += p * (float)hv.z; acc.w += p * (float)hv.w;
  }

  const float4 bv = *(const float4*)&bias[lane * 4];
  float v0 = acc.x * rd + bv.x, v1 = acc.y * rd + bv.y;
  float v2 = acc.z * rd + bv.z, v3 = acc.w * rd + bv.w;
  v0 = (v0 > 0.f) ? v0 : 0.01f * v0;
  v1 = (v1 > 0.f) ? v1 : 0.01f * v1;
  v2 = (v2 > 0.f) ? v2 : 0.01f * v2;
  v3 = (v3 > 0.f) ? v3 : 0.01f * v3;
  if (out) {
    float4 vout = {v0, v1, v2, v3};
    *(float4*)&out[(size_t)n * DMODEL + lane * 4] = vout;
  }
  bf16 b4[4] = {(bf16)v0, (bf16)v1, (bf16)v2, (bf16)v3};
  *(ulong1*)&outb[(size_t)n * DMODEL + lane * 4] = *(ulong1*)b4;
}

// ======================= LayerNorm(a+b) =======================
__global__ __launch_bounds__(256) void ln_kernel(
    const float* __restrict__ a, const float* __restrict__ b,
    const float* __restrict__ g, const float* __restrict__ beta,
    float* __restrict__ out, bf16* __restrict__ outb)
{
  int wave = threadIdx.x >> 6, lane = threadIdx.x & 63;
  int row = blockIdx.x * 4 + wave;
  const float* pa = a + (size_t)row * DMODEL;
  const float* pb = b + (size_t)row * DMODEL;
  float v[4];
  float s = 0.f;
#pragma unroll
  for (int i = 0; i < 4; i++) {
    v[i] = pa[lane + 64 * i] + pb[lane + 64 * i];
    s += v[i];
  }
#pragma unroll
  for (int o = 32; o; o >>= 1) s += __shfl_xor(s, o);
  float mu = s * (1.f / DMODEL);
  float s2 = 0.f;
#pragma unroll
  for (int i = 0; i < 4; i++) {
    float d = v[i] - mu;
    s2 += d * d;
  }
#pragma unroll
  for (int o = 32; o; o >>= 1) s2 += __shfl_xor(s2, o);
  float rstd = rsqrtf(s2 * (1.f / DMODEL) + 1e-5f);
  float* po = out + (size_t)row * DMODEL;
  bf16* pob = outb ? outb + (size_t)row * DMODEL : nullptr;
#pragma unroll
  for (int i = 0; i < 4; i++) {
    int c = lane + 64 * i;
    float ov = (v[i] - mu) * rstd * g[c] + beta[c];
    po[c] = ov;
    if (pob) pob[c] = (bf16)ov;
  }
}

// ======================= mean pool =======================
__global__ __launch_bounds__(256) void pool_kernel(const float* __restrict__ t, float* __restrict__ pooled)
{
  int g = blockIdx.x, part = blockIdx.y, ch = threadIdx.x;
  int r0 = part * 128;
  float s = 0.f;
  for (int i = 0; i < 128; i++) s += t[((size_t)g * SQLEN + r0 + i) * DMODEL + ch];
  atomicAdd(&pooled[g * DMODEL + ch], s * (1.0f / 1024.0f));
}

// ======================= final FC =======================
__global__ __launch_bounds__(256) void final_fc_kernel(
    const float* __restrict__ pooled, const float* __restrict__ W,
    const float* __restrict__ b, float* __restrict__ out)
{
  int g = blockIdx.y;
  int o = blockIdx.x * 256 + threadIdx.x;
  __shared__ float p[DMODEL];
  p[threadIdx.x] = pooled[g * DMODEL + threadIdx.x];
  __syncthreads();
  float s = b[o];
#pragma unroll 8
  for (int k = 0; k < DMODEL; k++) s += p[k] * W[(size_t)k * 1024 + o];
  out[(size_t)g * 1024 + o] = s;
}

// ======================= launch helpers =======================
static inline void gemm(const bf16* A, const bf16* Bt, const float* bias, float* Cf, bf16* Cb,
                        int M, int N, int K, int act, hipStream_t stream,
                        const float* gas = nullptr, const float* gad = nullptr,
                        float* ssrc = nullptr, float* sdst = nullptr)
{
  if (N == 256)
    mfma_gemm_t<64><<<dim3(N / 64, M / 128), 256, 0, stream>>>(A, Bt, bias, Cf, Cb, M, N, K, act,
                                                               gas, gad, ssrc, sdst);
  else
    mfma_gemm_t<128><<<dim3(N / 128, M / 128), 256, 0, stream>>>(A, Bt, bias, Cf, Cb, M, N, K, act,
                                                                 gas, gad, ssrc, sdst);
}

extern "C" void kernel_launch(void* const* d_in, const int* in_sizes, int n_in,
                              void* d_out, int out_size, void* d_ws, size_t ws_size,
                              hipStream_t stream)
{
  const int N = NNODES;
  const float* x    = (const float*)d_in[0];
  const int* esrc   = (const int*)d_in[1];
  const int* edst   = (const int*)d_in[2];
  const int E = in_sizes[1];
  const float* fc1W = (const float*)d_in[4];
  const float* fc1b = (const float*)d_in[5];
  const float* g0W  = (const float*)d_in[6];
  const float* g0as = (const float*)d_in[7];
  const float* g0ad = (const float*)d_in[8];
  const float* g0b  = (const float*)d_in[9];
  const float* gW   = (const float*)d_in[10];
  const float* gas  = (const float*)d_in[11];
  const float* gad  = (const float*)d_in[12];
  const float* gb   = (const float*)d_in[13];
  const float* saWq = (const float*)d_in[14]; const float* sabq = (const float*)d_in[15];
  const float* saWk = (const float*)d_in[16]; const float* sabk = (const float*)d_in[17];
  const float* saWv = (const float*)d_in[18]; const float* sabv = (const float*)d_in[19];
  const float* saWo = (const float*)d_in[20]; const float* sabo = (const float*)d_in[21];
  const float* caWq = (const float*)d_in[22]; const float* cabq = (const float*)d_in[23];
  const float* caWk = (const float*)d_in[24]; const float* cabk = (const float*)d_in[25];
  const float* caWv = (const float*)d_in[26]; const float* cabv = (const float*)d_in[27];
  const float* caWo = (const float*)d_in[28]; const float* cabo = (const float*)d_in[29];
  const float* ln1g = (const float*)d_in[30]; const float* ln1b = (const float*)d_in[31];
  const float* ln2g = (const float*)d_in[32]; const float* ln2b = (const float*)d_in[33];
  const float* ln3g = (const float*)d_in[34]; const float* ln3b = (const float*)d_in[35];
  const float* ff1W = (const float*)d_in[36]; const float* ff1b = (const float*)d_in[37];
  const float* ff2W = (const float*)d_in[38]; const float* ff2b = (const float*)d_in[39];
  const float* fcW  = (const float*)d_in[40]; const float* fcb  = (const float*)d_in[41];

  // ---------------- workspace layout ----------------
  float* ws = (float*)d_ws;
  const size_t NF = (size_t)N * DMODEL;
  float* A  = ws;            // residual t / t2 / t3 f32
  float* Bb = A + NF;        // f32 GEMM outs (Wo, ff2)
  float* Kb = Bb + NF;       // t1 f32
  bf16* P0   = (bf16*)(Kb + NF);
  bf16* P1   = P0 + NF;
  bf16* hWb  = P1 + NF;      // GAT gemm out; later aliased as cross-Q (Bq)
  bf16* Bqkv = hWb + NF;     // [N][768] fused self QKV; FF intermediate aliases here
  bf16* Bkv  = Bqkv + 3 * NF;  // [N][512] fused cross KV
  bf16* VtS  = Bkv + 2 * NF;
  bf16* VtC  = VtS + NF;
  bf16* Batt = VtC + NF;
  bf16* Bq   = hWb;          // cross-attn Q (hWb dead after GAT)
  bf16* FFIb = Bqkv;         // [N,1024] spans Bqkv + first part of Bkv (both dead)
  bf16* h0bf = Batt + NF;
  bf16* g0Wt = h0bf + (size_t)N * 64;
  bf16* gWt  = g0Wt + 256 * 64;
  bf16* saWqT = gWt + 3 * 65536;   // q,k,v contiguous -> fused N=768
  bf16* saWkT = saWqT + 65536;
  bf16* saWvT = saWkT + 65536;
  bf16* saWoT = saWvT + 65536;
  bf16* caWqT = saWoT + 65536;
  bf16* caWkT = caWqT + 65536;     // k,v contiguous -> fused N=512
  bf16* caWvT = caWkT + 65536;
  bf16* caWoT = caWvT + 65536;
  bf16* ff1Wt = caWoT + 65536;
  bf16* ff2Wt = ff1Wt + 262144;
  float* ssrc = (float*)(ff2Wt + 262144);
  float* sdst = ssrc + (size_t)N * 4;
  float* qkvb = sdst + (size_t)N * 4;   // [768]
  float* kvb  = qkvb + 768;             // [512]
  float* pooled = kvb + 512;
  int* cnt  = (int*)(pooled + NGRAPH * DMODEL);
  int* offs = cnt + N;
  int* cur  = offs + N + 1;
  int* csr  = cur + N;

  // ---------------- weight prep ----------------
  W11 wl;
  const float* srcs[11] = {gW, gW + 65536, gW + 2 * 65536, saWq, saWk, saWv, saWo, caWq, caWk, caWv, caWo};
  bf16* dsts[11] = {gWt, gWt + 65536, gWt + 2 * 65536, saWqT, saWkT, saWvT, saWoT, caWqT, caWkT, caWvT, caWoT};
  for (int i = 0; i < 11; i++) { wl.s[i] = srcs[i]; wl.d[i] = dsts[i]; }
  transpose11_kernel<<<dim3(8, 8, 11), 256, 0, stream>>>(wl);
  transpose_kernel<<<dim3(8, 2), 256, 0, stream>>>(g0W, g0Wt, 64, 256);
  transpose_kernel<<<dim3(32, 8), 256, 0, stream>>>(ff1W, ff1Wt, 256, 1024);
  transpose_kernel<<<dim3(8, 32), 256, 0, stream>>>(ff2W, ff2Wt, 1024, 256);

  // fused bias vectors (d2d copies are graph-capture safe)
  hipMemcpyAsync(qkvb,       sabq, 256 * sizeof(float), hipMemcpyDeviceToDevice, stream);
  hipMemcpyAsync(qkvb + 256, sabk, 256 * sizeof(float), hipMemcpyDeviceToDevice, stream);
  hipMemcpyAsync(qkvb + 512, sabv, 256 * sizeof(float), hipMemcpyDeviceToDevice, stream);
  hipMemcpyAsync(kvb,        cabk, 256 * sizeof(float), hipMemcpyDeviceToDevice, stream);
  hipMemcpyAsync(kvb + 256,  cabv, 256 * sizeof(float), hipMemcpyDeviceToDevice, stream);

  // ---------------- CSR build ----------------
  hipMemsetAsync(cnt, 0, N * sizeof(int), stream);
  hist_kernel<<<(E + 255) / 256, 256, 0, stream>>>(edst, cnt, E);
  scan_kernel<<<1, 256, 0, stream>>>(cnt, offs, cur, N);
  scatter_kernel<<<(E + 255) / 256, 256, 0, stream>>>(esrc, edst, cur, csr, E);

  // ---------------- fc1 + GAT stack ----------------
  fc1_kernel<<<(N * 64) / 256, 256, 0, stream>>>(x, fc1W, fc1b, h0bf);

  gemm(h0bf, g0Wt, nullptr, nullptr, hWb, N, DMODEL, 64, 0, stream, g0as, g0ad, ssrc, sdst);
  gat_fused_kernel<<<N / 4, 256, 0, stream>>>(hWb, offs, csr, ssrc, sdst, g0b, nullptr, P0);

  bf16* pin = P0; bf16* pout = P1;
  for (int i = 0; i < 3; i++) {
    gemm(pin, gWt + (size_t)i * 65536, nullptr, nullptr, hWb, N, DMODEL, DMODEL, 0, stream,
         gas + i * 256, gad + i * 256, ssrc, sdst);
    gat_fused_kernel<<<N / 4, 256, 0, stream>>>(hWb, offs, csr, ssrc, sdst, gb + i * DMODEL,
                                                (i == 2) ? A : nullptr, pout);
    bf16* tmp = pin; pin = pout; pout = tmp;
  }
  bf16* tbf = pin;  // t bf16; t f32 in A

  // ---------------- cross-attn fused K/V from mem ----------------
  gemm(tbf, caWkT, kvb, nullptr, Bkv, N, 512, DMODEL, 0, stream);
  vtrans_kernel<<<dim3(32, 8, NGRAPH), 256, 0, stream>>>(Bkv, 512, 256, VtC);

  // ---------------- self-attention (fused QKV) ----------------
  gemm(tbf, saWqT, qkvb, nullptr, Bqkv, N, 768, DMODEL, 0, stream);
  vtrans_kernel<<<dim3(32, 8, NGRAPH), 256, 0, stream>>>(Bqkv, 768, 512, VtS);
  attn_mfma_kernel<<<dim3(SQLEN / 64, 2, NGRAPH), 256, 0, stream>>>(
      Bqkv, 768, Bqkv + 256, 768, VtS, Batt);
  gemm(Batt, saWoT, sabo, Bb, nullptr, N, DMODEL, DMODEL, 0, stream);
  ln_kernel<<<N / 4, 256, 0, stream>>>(A, Bb, ln1g, ln1b, Kb, P0);  // t1

  // ---------------- cross-attention ----------------
  gemm(P0, caWqT, cabq, nullptr, Bq, N, DMODEL, DMODEL, 0, stream);
  attn_mfma_kernel<<<dim3(SQLEN / 64, 2, NGRAPH), 256, 0, stream>>>(
      Bq, 256, Bkv, 512, VtC, Batt);
  gemm(Batt, caWoT, cabo, Bb, nullptr, N, DMODEL, DMODEL, 0, stream);
  ln_kernel<<<N / 4, 256, 0, stream>>>(Kb, Bb, ln2g, ln2b, A, P0);  // t2

  // ---------------- feed-forward ----------------
  gemm(P0, ff1Wt, ff1b, nullptr, FFIb, N, 1024, DMODEL, 1, stream);  // relu
  gemm(FFIb, ff2Wt, ff2b, Bb, nullptr, N, DMODEL, 1024, 0, stream);
  ln_kernel<<<N / 4, 256, 0, stream>>>(A, Bb, ln3g, ln3b, A, nullptr);  // t3

  // ---------------- pool + final FC ----------------
  hipMemsetAsync(pooled, 0, NGRAPH * DMODEL * sizeof(float), stream);
  pool_kernel<<<dim3(NGRAPH, 8), 256, 0, stream>>>(A, pooled);
  final_fc_kernel<<<dim3(4, NGRAPH), 256, 0, stream>>>(pooled, fcW, fcb, (float*)d_out);
}

// Round 9
// 653.245 us; speedup vs baseline: 1.0367x; 1.0367x over previous
//
#include <hip/hip_runtime.h>
#include <cstddef>

#define NNODES 16384
#define DMODEL 256
#define CCH 64
#define SQLEN 1024
#define NGRAPH 16
#define ADH 128

typedef __bf16 bf16;
typedef __attribute__((ext_vector_type(8))) __bf16 bf16x8;
typedef __attribute__((ext_vector_type(4))) __bf16 bf16x4;
typedef __attribute__((ext_vector_type(4))) float floatx4;

// ======================= bf16 MFMA GEMM: C[M,N] = A[M,K] @ Bt[N,K]^T =======================
template <int BN>
__global__ __launch_bounds__(256) void mfma_gemm_t(
    const bf16* __restrict__ A, const bf16* __restrict__ Bt,
    const float* __restrict__ bias, float* __restrict__ Cf, bf16* __restrict__ Cb,
    int M, int N, int K, int act,
    const float* __restrict__ gas, const float* __restrict__ gad,
    float* __restrict__ ssrc, float* __restrict__ sdst)
{
  constexpr int BM = 128;
  constexpr int MW = (BN == 128) ? 4 : 2;
  constexpr int NW = 4;
  constexpr int ACH = BM / 8;
  constexpr int TCH = (BM + BN) / 8;
  __shared__ bf16 As[BM * 64];
  __shared__ bf16 Bs[BN * 64];
  const int tid = threadIdx.x;
  const int wave = tid >> 6, lane = tid & 63;
  const int m0 = blockIdx.y * BM, n0 = blockIdx.x * BN;
  const int lr = lane & 15, quad = lane >> 4;
  const int wm = (BN == 128) ? (wave >> 1) * 64 : wave * 32;
  const int wn = (BN == 128) ? (wave & 1) * 64 : 0;
  const int r8 = lane >> 3, cu = lane & 7;
  const int scol = (cu ^ r8) * 8;

  floatx4 acc[MW][NW];
  const floatx4 zero = {0.f, 0.f, 0.f, 0.f};
#pragma unroll
  for (int i = 0; i < MW; i++)
#pragma unroll
    for (int j = 0; j < NW; j++) acc[i][j] = zero;

  for (int k0 = 0; k0 < K; k0 += 64) {
#pragma unroll
    for (int c = wave; c < TCH; c += 4) {
      const bf16* g;
      bf16* l;
      if (c < ACH) {
        g = A + (size_t)(m0 + c * 8 + r8) * K + k0 + scol;
        l = &As[c * 512];
      } else {
        int c2 = c - ACH;
        g = Bt + (size_t)(n0 + c2 * 8 + r8) * K + k0 + scol;
        l = &Bs[c2 * 512];
      }
      __builtin_amdgcn_global_load_lds(
          (const __attribute__((address_space(1))) void*)g,
          (__attribute__((address_space(3))) void*)l, 16, 0, 0);
    }
    __syncthreads();
#pragma unroll
    for (int ks = 0; ks < 2; ks++) {
      bf16x8 af[MW], bfr[NW];
#pragma unroll
      for (int i = 0; i < MW; i++) {
        int row = wm + i * 16 + lr;
        af[i] = *(const bf16x8*)&As[(row * 8 + ((ks * 4 + quad) ^ (row & 7))) * 8];
      }
#pragma unroll
      for (int i = 0; i < NW; i++) {
        int row = wn + i * 16 + lr;
        bfr[i] = *(const bf16x8*)&Bs[(row * 8 + ((ks * 4 + quad) ^ (row & 7))) * 8];
      }
#pragma unroll
      for (int mi = 0; mi < MW; mi++)
#pragma unroll
        for (int ni = 0; ni < NW; ni++)
          acc[mi][ni] = __builtin_amdgcn_mfma_f32_16x16x32_bf16(af[mi], bfr[ni], acc[mi][ni], 0, 0, 0);
    }
    __syncthreads();
  }

  float as_v[4], ad_v[4];
  int head = 0;
  if (gas) {
    head = (n0 + wn) >> 6;
#pragma unroll
    for (int ni = 0; ni < 4; ni++) {
      as_v[ni] = gas[head * 64 + ni * 16 + lr];
      ad_v[ni] = gad[head * 64 + ni * 16 + lr];
    }
  }

#pragma unroll
  for (int mi = 0; mi < MW; mi++) {
    int rbase = m0 + wm + mi * 16 + quad * 4;
#pragma unroll
    for (int r = 0; r < 4; r++) {
      int row = rbase + r;
      float s1 = 0.f, s2 = 0.f;
#pragma unroll
      for (int ni = 0; ni < NW; ni++) {
        int col = n0 + wn + ni * 16 + lr;
        float v = acc[mi][ni][r];
        if (gas) { s1 += v * as_v[ni]; s2 += v * ad_v[ni]; }
        if (bias) v += bias[col];
        if (act == 1) v = fmaxf(v, 0.f);
        if (Cf) Cf[(size_t)row * N + col] = v;
        if (Cb) Cb[(size_t)row * N + col] = (bf16)v;
      }
      if (gas) {
        s1 += __shfl_xor(s1, 1); s1 += __shfl_xor(s1, 2);
        s1 += __shfl_xor(s1, 4); s1 += __shfl_xor(s1, 8);
        s2 += __shfl_xor(s2, 1); s2 += __shfl_xor(s2, 2);
        s2 += __shfl_xor(s2, 4); s2 += __shfl_xor(s2, 8);
        if (lr == 0) {
          ssrc[row * 4 + head] = s1;
          sdst[row * 4 + head] = s2;
        }
      }
    }
  }
}

// ======================= fused prep: all weight transposes + biases + cnt zero + fc1 =======================
struct PrepArgs {
  const float* sq[11]; bf16* dq[11];
  const float* g0W; bf16* g0Wt;
  const float* ff1W; bf16* ff1Wt;
  const float* ff2W; bf16* ff2Wt;
  const float* sabq; const float* sabk; const float* sabv;
  const float* cabk; const float* cabv;
  float* qkvb; float* kvb;
  int* cnt;
  const float* x; const float* fc1W; const float* fc1b; bf16* h0;
};

__global__ __launch_bounds__(256) void prep_kernel(PrepArgs a)
{
  __shared__ float t[32][33];
  int b = blockIdx.x;
  int tid = threadIdx.x;
  int tx = tid & 31, ty = tid >> 5;
  if (b < 704) {  // 11 square 256x256 transposes, 64 tiles each
    int w = b >> 6, tile = b & 63;
    int n0 = (tile & 7) * 32, k0 = (tile >> 3) * 32;
    const float* W = a.sq[w];
    bf16* Wt = a.dq[w];
#pragma unroll
    for (int i = 0; i < 4; i++) t[ty + 8 * i][tx] = W[(size_t)(k0 + ty + 8 * i) * 256 + n0 + tx];
    __syncthreads();
#pragma unroll
    for (int i = 0; i < 4; i++) Wt[(size_t)(n0 + ty + 8 * i) * 256 + k0 + tx] = (bf16)t[tx][ty + 8 * i];
  } else if (b < 720) {  // g0W [64,256] -> [256][64]
    int tile = b - 704;
    int n0 = (tile & 7) * 32, k0 = (tile >> 3) * 32;
#pragma unroll
    for (int i = 0; i < 4; i++) t[ty + 8 * i][tx] = a.g0W[(size_t)(k0 + ty + 8 * i) * 256 + n0 + tx];
    __syncthreads();
#pragma unroll
    for (int i = 0; i < 4; i++) a.g0Wt[(size_t)(n0 + ty + 8 * i) * 64 + k0 + tx] = (bf16)t[tx][ty + 8 * i];
  } else if (b < 976) {  // ff1W [256,1024] -> [1024][256]
    int tile = b - 720;
    int n0 = (tile & 31) * 32, k0 = (tile >> 5) * 32;
#pragma unroll
    for (int i = 0; i < 4; i++) t[ty + 8 * i][tx] = a.ff1W[(size_t)(k0 + ty + 8 * i) * 1024 + n0 + tx];
    __syncthreads();
#pragma unroll
    for (int i = 0; i < 4; i++) a.ff1Wt[(size_t)(n0 + ty + 8 * i) * 256 + k0 + tx] = (bf16)t[tx][ty + 8 * i];
  } else if (b < 1232) {  // ff2W [1024,256] -> [256][1024]
    int tile = b - 976;
    int n0 = (tile & 7) * 32, k0 = (tile >> 3) * 32;
#pragma unroll
    for (int i = 0; i < 4; i++) t[ty + 8 * i][tx] = a.ff2W[(size_t)(k0 + ty + 8 * i) * 256 + n0 + tx];
    __syncthreads();
#pragma unroll
    for (int i = 0; i < 4; i++) a.ff2Wt[(size_t)(n0 + ty + 8 * i) * 1024 + k0 + tx] = (bf16)t[tx][ty + 8 * i];
  } else if (b == 1232) {  // fused bias vectors
    a.qkvb[tid] = a.sabq[tid];
    a.qkvb[256 + tid] = a.sabk[tid];
    a.qkvb[512 + tid] = a.sabv[tid];
    a.kvb[tid] = a.cabk[tid];
    a.kvb[256 + tid] = a.cabv[tid];
  } else if (b < 1249) {  // zero cnt[16384]
    int i0 = (b - 1233) * 1024 + tid;
#pragma unroll
    for (int i = 0; i < 4; i++) a.cnt[i0 + 256 * i] = 0;
  } else {  // fc1: [N,16]@[16,64]+b -> bf16
    int idx = (b - 1249) * 256 + tid;
    int n = idx >> 6, j = idx & 63;
    const float* xr = a.x + (size_t)n * 16;
    float s = a.fc1b[j];
#pragma unroll
    for (int k = 0; k < 16; k++) s += xr[k] * a.fc1W[k * 64 + j];
    a.h0[idx] = (bf16)s;
  }
}

// ======================= V transpose (both attention sources in one dispatch) =======================
__global__ __launch_bounds__(256) void vtrans2_kernel(const bf16* __restrict__ Vc, const bf16* __restrict__ Vs,
                                                      bf16* __restrict__ VtC, bf16* __restrict__ VtS)
{
  __shared__ bf16 t[32][34];
  int z = blockIdx.z;
  const bf16* V;
  bf16* Vt;
  int ldv, coff, b;
  if (z < NGRAPH) { V = Vc; Vt = VtC; ldv = 512; coff = 256; b = z; }
  else            { V = Vs; Vt = VtS; ldv = 768; coff = 512; b = z - NGRAPH; }
  int head = blockIdx.y >> 2, d0 = (blockIdx.y & 3) * 32;
  int k0 = blockIdx.x * 32;
  int tx = threadIdx.x & 31, ty = threadIdx.x >> 5;
#pragma unroll
  for (int i = 0; i < 4; i++)
    t[ty + 8 * i][tx] = V[((size_t)(b * SQLEN + k0 + ty + 8 * i)) * ldv + coff + head * ADH + d0 + tx];
  __syncthreads();
#pragma unroll
  for (int i = 0; i < 4; i++)
    Vt[((size_t)((b * 2 + head) * ADH) + d0 + ty + 8 * i) * SQLEN + k0 + tx] = t[tx][ty + 8 * i];
}

// ======================= MFMA flash attention — S^T operand order, static-max softmax =======================
__global__ __launch_bounds__(256) void attn_mfma_kernel(
    const bf16* __restrict__ Q, int ldq, const bf16* __restrict__ K, int ldk,
    const bf16* __restrict__ Vt, bf16* __restrict__ O)
{
  const int qt = blockIdx.x, head = blockIdx.y, b = blockIdx.z;
  const int tid = threadIdx.x, wave = tid >> 6, lane = tid & 63;
  const int lr = lane & 15, quad = lane >> 4;

  __shared__ __align__(16) bf16 Ks[2][64 * 128];
  __shared__ __align__(16) bf16 Vts[2][128 * 64];
  __shared__ __align__(16) bf16 Ps[4][16][72];

  const int q0 = qt * 64 + wave * 16;
  const size_t qrow = ((size_t)b * SQLEN + q0 + lr) * ldq + head * ADH;
  const float scale2 = 0.08838834764831845f * 1.4426950408889634f;  // log2e/sqrt(128)
  bf16x8 qf[4];
#pragma unroll
  for (int s = 0; s < 4; s++) {
    qf[s] = *(const bf16x8*)&Q[qrow + s * 32 + quad * 8];
#pragma unroll
    for (int j = 0; j < 8; j++) qf[s][j] = (bf16)((float)qf[s][j] * scale2);
  }

  floatx4 accO[8];
  const floatx4 zero = {0.f, 0.f, 0.f, 0.f};
#pragma unroll
  for (int n = 0; n < 8; n++) accO[n] = zero;
  float lsum = 0.f;

  const bf16* kbase = K + ((size_t)b * SQLEN) * ldk + head * ADH;
  const bf16* vtb = Vt + ((size_t)((b * 2 + head) * ADH)) * SQLEN;

  auto stage = [&](int buf, int k0) {
#pragma unroll
    for (int p = 0; p < 4; p++) {
      int bu = p * 256 + wave * 64;
      int u = bu + lane;
      int r = u >> 4, cq = u & 15;
      int c = cq ^ (r & 7);
      __builtin_amdgcn_global_load_lds(
          (const __attribute__((address_space(1))) void*)(kbase + (size_t)(k0 + r) * ldk + c * 8),
          (__attribute__((address_space(3))) void*)&Ks[buf][bu * 8], 16, 0, 0);
    }
#pragma unroll
    for (int p = 0; p < 4; p++) {
      int bu = p * 256 + wave * 64;
      int u = bu + lane;
      int r = u >> 3, cq = u & 7;
      int c = cq ^ (r & 7);
      __builtin_amdgcn_global_load_lds(
          (const __attribute__((address_space(1))) void*)(vtb + (size_t)r * SQLEN + k0 + c * 8),
          (__attribute__((address_space(3))) void*)&Vts[buf][bu * 8], 16, 0, 0);
    }
  };

  stage(0, 0);
  for (int it = 0; it < 16; it++) {
    __syncthreads();
    if (it < 15) stage((it + 1) & 1, (it + 1) * 64);
    const bf16* ks = Ks[it & 1];
    const bf16* vs = Vts[it & 1];

    floatx4 accS[4];
#pragma unroll
    for (int i = 0; i < 4; i++) accS[i] = zero;
#pragma unroll
    for (int i = 0; i < 4; i++) {
#pragma unroll
      for (int s = 0; s < 4; s++) {
        int r = i * 16 + lr;
        int cpr = (s * 4 + quad) ^ (r & 7);
        bf16x8 kf = *(const bf16x8*)&ks[(r * 16 + cpr) * 8];
        accS[i] = __builtin_amdgcn_mfma_f32_16x16x32_bf16(kf, qf[s], accS[i], 0, 0, 0);
      }
    }

#pragma unroll
    for (int i = 0; i < 4; i++) {
      bf16x4 pk;
#pragma unroll
      for (int r = 0; r < 4; r++) {
        float p = exp2f(accS[i][r]);
        pk[r] = (bf16)p;
        lsum += p;
      }
      *(bf16x4*)&Ps[wave][lr][i * 16 + quad * 4] = pk;
    }

    bf16x8 pf[2];
#pragma unroll
    for (int s = 0; s < 2; s++) pf[s] = *(const bf16x8*)&Ps[wave][lr][s * 32 + quad * 8];
#pragma unroll
    for (int n = 0; n < 8; n++) {
#pragma unroll
      for (int s = 0; s < 2; s++) {
        int r = n * 16 + lr;
        int cpr = (s * 4 + quad) ^ (r & 7);
        bf16x8 vf = *(const bf16x8*)&vs[(r * 8 + cpr) * 8];
        accO[n] = __builtin_amdgcn_mfma_f32_16x16x32_bf16(pf[s], vf, accO[n], 0, 0, 0);
      }
    }
  }

  lsum += __shfl_xor(lsum, 16);
  lsum += __shfl_xor(lsum, 32);
  float linv[4];
#pragma unroll
  for (int r = 0; r < 4; r++) linv[r] = 1.f / __shfl(lsum, quad * 4 + r);
  size_t obase = ((size_t)b * SQLEN + q0 + quad * 4) * DMODEL + head * ADH;
#pragma unroll
  for (int n = 0; n < 8; n++)
#pragma unroll
    for (int r = 0; r < 4; r++)
      O[obase + (size_t)r * DMODEL + n * 16 + lr] = (bf16)(accO[n][r] * linv[r]);
}

// ======================= CSR build =======================
__global__ __launch_bounds__(256) void hist_kernel(const int* __restrict__ dst, int* __restrict__ cnt, int E)
{
  int e = blockIdx.x * 256 + threadIdx.x;
  if (e < E) atomicAdd(&cnt[dst[e]], 1);
}

__global__ __launch_bounds__(256) void scan_kernel(const int* __restrict__ cnt, int* __restrict__ offs,
                                                   int* __restrict__ cur, int n)
{
  __shared__ int partial[256];
  int tid = threadIdx.x;
  int chunk = n / 256;
  int base = tid * chunk;
  int s = 0;
  for (int i = 0; i < chunk; i++) s += cnt[base + i];
  partial[tid] = s;
  __syncthreads();
  for (int off = 1; off < 256; off <<= 1) {
    int v = 0;
    if (tid >= off) v = partial[tid - off];
    __syncthreads();
    partial[tid] += v;
    __syncthreads();
  }
  int run = partial[tid] - s;
  for (int i = 0; i < chunk; i++) {
    offs[base + i] = run;
    cur[base + i] = run;
    run += cnt[base + i];
  }
  if (tid == 255) offs[n] = run;
}

__global__ __launch_bounds__(256) void scatter_kernel(const int* __restrict__ src, const int* __restrict__ dst,
                                                      int* __restrict__ cur, int* __restrict__ csr, int E)
{
  int e = blockIdx.x * 256 + threadIdx.x;
  if (e < E) {
    int p = atomicAdd(&cur[dst[e]], 1);
    csr[p] = src[e];
  }
}

// ======================= fused GAT softmax + aggregation (one wave per node) =======================
__global__ __launch_bounds__(256) void gat_fused_kernel(
    const bf16* __restrict__ hW, const int* __restrict__ offs, const int* __restrict__ csr,
    const float* __restrict__ ssrc, const float* __restrict__ sdst,
    const float* __restrict__ bias, float* __restrict__ out, bf16* __restrict__ outb)
{
  __shared__ float pL[4][128][4];
  int wave = threadIdx.x >> 6, lane = threadIdx.x & 63;
  int n = blockIdx.x * 4 + wave;
  int row0 = offs[n], row1 = offs[n + 1];
  int deg = row1 - row0;

  int src_reg = (lane < deg) ? csr[row0 + lane] : 0;

  int h1 = lane & 3, el = lane >> 2;
  float sd = sdst[n * 4 + h1];
  float m = -1e30f;
  for (int e = el; e < deg; e += 16) {
    int src = (e < 64) ? __shfl(src_reg, e) : csr[row0 + e];
    float sc = ssrc[src * 4 + h1] + sd;
    sc = (sc > 0.f) ? sc : 0.2f * sc;
    if (e < 128) pL[wave][e][h1] = sc;
    m = fmaxf(m, sc);
  }
  m = fmaxf(m, __shfl_xor(m, 4));
  m = fmaxf(m, __shfl_xor(m, 8));
  m = fmaxf(m, __shfl_xor(m, 16));
  m = fmaxf(m, __shfl_xor(m, 32));
  float den = 0.f;
  for (int e = el; e < deg; e += 16) {
    float sc;
    if (e < 128) sc = pL[wave][e][h1];
    else {
      int src = csr[row0 + e];
      sc = ssrc[src * 4 + h1] + sd;
      sc = (sc > 0.f) ? sc : 0.2f * sc;
    }
    float p = __expf(sc - m);
    if (e < 128) pL[wave][e][h1] = p;
    den += p;
  }
  den += __shfl_xor(den, 4);
  den += __shfl_xor(den, 8);
  den += __shfl_xor(den, 16);
  den += __shfl_xor(den, 32);
  float rd1 = 1.f / (den + 1e-16f);

  int h2 = lane >> 4;
  float rd = __shfl(rd1, h2);
  float m2 = __shfl(m, h2);
  float sd2 = __shfl(sd, h2);
  float4 acc = {0.f, 0.f, 0.f, 0.f};
  for (int i = 0; i < deg; i++) {
    int src = (i < 64) ? __shfl(src_reg, i) : csr[row0 + i];
    float p;
    if (i < 128) p = pL[wave][i][h2];
    else {
      float sc = ssrc[src * 4 + h2] + sd2;
      sc = (sc > 0.f) ? sc : 0.2f * sc;
      p = __expf(sc - m2);
    }
    bf16x4 hv = *(const bf16x4*)&hW[(size_t)src * DMODEL + lane * 4];
    acc.x += p * (float)hv.x; acc.y += p * (float)hv.y;
    acc.z += p * (float)hv.z; acc.w += p * (float)hv.w;
  }

  const float4 bv = *(const float4*)&bias[lane * 4];
  float v0 = acc.x * rd + bv.x, v1 = acc.y * rd + bv.y;
  float v2 = acc.z * rd + bv.z, v3 = acc.w * rd + bv.w;
  v0 = (v0 > 0.f) ? v0 : 0.01f * v0;
  v1 = (v1 > 0.f) ? v1 : 0.01f * v1;
  v2 = (v2 > 0.f) ? v2 : 0.01f * v2;
  v3 = (v3 > 0.f) ? v3 : 0.01f * v3;
  if (out) {
    float4 vout = {v0, v1, v2, v3};
    *(float4*)&out[(size_t)n * DMODEL + lane * 4] = vout;
  }
  bf16 b4[4] = {(bf16)v0, (bf16)v1, (bf16)v2, (bf16)v3};
  *(ulong1*)&outb[(size_t)n * DMODEL + lane * 4] = *(ulong1*)b4;
}

// ======================= LayerNorm(a+b), optional pooled-zero side-effect =======================
__global__ __launch_bounds__(256) void ln_kernel(
    const float* __restrict__ a, const float* __restrict__ b,
    const float* __restrict__ g, const float* __restrict__ beta,
    float* __restrict__ out, bf16* __restrict__ outb, float* __restrict__ pz)
{
  if (pz && blockIdx.x < 16) pz[blockIdx.x * 256 + threadIdx.x] = 0.f;
  int wave = threadIdx.x >> 6, lane = threadIdx.x & 63;
  int row = blockIdx.x * 4 + wave;
  const float* pa = a + (size_t)row * DMODEL;
  const float* pb = b + (size_t)row * DMODEL;
  float v[4];
  float s = 0.f;
#pragma unroll
  for (int i = 0; i < 4; i++) {
    v[i] = pa[lane + 64 * i] + pb[lane + 64 * i];
    s += v[i];
  }
#pragma unroll
  for (int o = 32; o; o >>= 1) s += __shfl_xor(s, o);
  float mu = s * (1.f / DMODEL);
  float s2 = 0.f;
#pragma unroll
  for (int i = 0; i < 4; i++) {
    float d = v[i] - mu;
    s2 += d * d;
  }
#pragma unroll
  for (int o = 32; o; o >>= 1) s2 += __shfl_xor(s2, o);
  float rstd = rsqrtf(s2 * (1.f / DMODEL) + 1e-5f);
  float* po = out + (size_t)row * DMODEL;
  bf16* pob = outb ? outb + (size_t)row * DMODEL : nullptr;
#pragma unroll
  for (int i = 0; i < 4; i++) {
    int c = lane + 64 * i;
    float ov = (v[i] - mu) * rstd * g[c] + beta[c];
    po[c] = ov;
    if (pob) pob[c] = (bf16)ov;
  }
}

// ======================= mean pool =======================
__global__ __launch_bounds__(256) void pool_kernel(const float* __restrict__ t, float* __restrict__ pooled)
{
  int g = blockIdx.x, part = blockIdx.y, ch = threadIdx.x;
  int r0 = part * 128;
  float s = 0.f;
  for (int i = 0; i < 128; i++) s += t[((size_t)g * SQLEN + r0 + i) * DMODEL + ch];
  atomicAdd(&pooled[g * DMODEL + ch], s * (1.0f / 1024.0f));
}

// ======================= final FC =======================
__global__ __launch_bounds__(256) void final_fc_kernel(
    const float* __restrict__ pooled, const float* __restrict__ W,
    const float* __restrict__ b, float* __restrict__ out)
{
  int g = blockIdx.y;
  int o = blockIdx.x * 256 + threadIdx.x;
  __shared__ float p[DMODEL];
  p[threadIdx.x] = pooled[g * DMODEL + threadIdx.x];
  __syncthreads();
  float s = b[o];
#pragma unroll 8
  for (int k = 0; k < DMODEL; k++) s += p[k] * W[(size_t)k * 1024 + o];
  out[(size_t)g * 1024 + o] = s;
}

// ======================= launch helpers =======================
static inline void gemm(const bf16* A, const bf16* Bt, const float* bias, float* Cf, bf16* Cb,
                        int M, int N, int K, int act, hipStream_t stream,
                        const float* gas = nullptr, const float* gad = nullptr,
                        float* ssrc = nullptr, float* sdst = nullptr)
{
  if (N == 256)
    mfma_gemm_t<64><<<dim3(N / 64, M / 128), 256, 0, stream>>>(A, Bt, bias, Cf, Cb, M, N, K, act,
                                                               gas, gad, ssrc, sdst);
  else
    mfma_gemm_t<128><<<dim3(N / 128, M / 128), 256, 0, stream>>>(A, Bt, bias, Cf, Cb, M, N, K, act,
                                                                 gas, gad, ssrc, sdst);
}

extern "C" void kernel_launch(void* const* d_in, const int* in_sizes, int n_in,
                              void* d_out, int out_size, void* d_ws, size_t ws_size,
                              hipStream_t stream)
{
  const int N = NNODES;
  const float* x    = (const float*)d_in[0];
  const int* esrc   = (const int*)d_in[1];
  const int* edst   = (const int*)d_in[2];
  const int E = in_sizes[1];
  const float* fc1W = (const float*)d_in[4];
  const float* fc1b = (const float*)d_in[5];
  const float* g0W  = (const float*)d_in[6];
  const float* g0as = (const float*)d_in[7];
  const float* g0ad = (const float*)d_in[8];
  const float* g0b  = (const float*)d_in[9];
  const float* gW   = (const float*)d_in[10];
  const float* gas  = (const float*)d_in[11];
  const float* gad  = (const float*)d_in[12];
  const float* gb   = (const float*)d_in[13];
  const float* saWq = (const float*)d_in[14]; const float* sabq = (const float*)d_in[15];
  const float* saWk = (const float*)d_in[16]; const float* sabk = (const float*)d_in[17];
  const float* saWv = (const float*)d_in[18]; const float* sabv = (const float*)d_in[19];
  const float* saWo = (const float*)d_in[20]; const float* sabo = (const float*)d_in[21];
  const float* caWq = (const float*)d_in[22]; const float* cabq = (const float*)d_in[23];
  const float* caWk = (const float*)d_in[24]; const float* cabk = (const float*)d_in[25];
  const float* caWv = (const float*)d_in[26]; const float* cabv = (const float*)d_in[27];
  const float* caWo = (const float*)d_in[28]; const float* cabo = (const float*)d_in[29];
  const float* ln1g = (const float*)d_in[30]; const float* ln1b = (const float*)d_in[31];
  const float* ln2g = (const float*)d_in[32]; const float* ln2b = (const float*)d_in[33];
  const float* ln3g = (const float*)d_in[34]; const float* ln3b = (const float*)d_in[35];
  const float* ff1W = (const float*)d_in[36]; const float* ff1b = (const float*)d_in[37];
  const float* ff2W = (const float*)d_in[38]; const float* ff2b = (const float*)d_in[39];
  const float* fcW  = (const float*)d_in[40]; const float* fcb  = (const float*)d_in[41];

  // ---------------- workspace layout ----------------
  float* ws = (float*)d_ws;
  const size_t NF = (size_t)N * DMODEL;
  float* A  = ws;            // residual t / t2 / t3 f32
  float* Bb = A + NF;        // f32 GEMM outs (Wo, ff2)
  float* Kb = Bb + NF;       // t1 f32
  bf16* P0   = (bf16*)(Kb + NF);
  bf16* P1   = P0 + NF;
  bf16* hWb  = P1 + NF;      // GAT gemm out; later aliased as cross-Q (Bq)
  bf16* Bqkv = hWb + NF;     // [N][768] fused self QKV; FF intermediate aliases here
  bf16* Bkv  = Bqkv + 3 * NF;  // [N][512] fused cross KV
  bf16* VtS  = Bkv + 2 * NF;
  bf16* VtC  = VtS + NF;
  bf16* Batt = VtC + NF;
  bf16* Bq   = hWb;          // cross-attn Q (hWb dead after GAT)
  bf16* FFIb = Bqkv;         // [N,1024] spans Bqkv + first part of Bkv (both dead)
  bf16* h0bf = Batt + NF;
  bf16* g0Wt = h0bf + (size_t)N * 64;
  bf16* gWt  = g0Wt + 256 * 64;
  bf16* saWqT = gWt + 3 * 65536;   // q,k,v contiguous -> fused N=768
  bf16* saWkT = saWqT + 65536;
  bf16* saWvT = saWkT + 65536;
  bf16* saWoT = saWvT + 65536;
  bf16* caWqT = saWoT + 65536;
  bf16* caWkT = caWqT + 65536;     // k,v contiguous -> fused N=512
  bf16* caWvT = caWkT + 65536;
  bf16* caWoT = caWvT + 65536;
  bf16* ff1Wt = caWoT + 65536;
  bf16* ff2Wt = ff1Wt + 262144;
  float* ssrc = (float*)(ff2Wt + 262144);
  float* sdst = ssrc + (size_t)N * 4;
  float* qkvb = sdst + (size_t)N * 4;   // [768]
  float* kvb  = qkvb + 768;             // [512]
  float* pooled = kvb + 512;
  int* cnt  = (int*)(pooled + NGRAPH * DMODEL);
  int* offs = cnt + N;
  int* cur  = offs + N + 1;
  int* csr  = cur + N;

  // ---------------- fused prep (all transposes + biases + cnt zero + fc1) ----------------
  PrepArgs pa;
  const float* srcs[11] = {gW, gW + 65536, gW + 2 * 65536, saWq, saWk, saWv, saWo, caWq, caWk, caWv, caWo};
  bf16* dsts[11] = {gWt, gWt + 65536, gWt + 2 * 65536, saWqT, saWkT, saWvT, saWoT, caWqT, caWkT, caWvT, caWoT};
  for (int i = 0; i < 11; i++) { pa.sq[i] = srcs[i]; pa.dq[i] = dsts[i]; }
  pa.g0W = g0W; pa.g0Wt = g0Wt;
  pa.ff1W = ff1W; pa.ff1Wt = ff1Wt;
  pa.ff2W = ff2W; pa.ff2Wt = ff2Wt;
  pa.sabq = sabq; pa.sabk = sabk; pa.sabv = sabv;
  pa.cabk = cabk; pa.cabv = cabv;
  pa.qkvb = qkvb; pa.kvb = kvb;
  pa.cnt = cnt;
  pa.x = x; pa.fc1W = fc1W; pa.fc1b = fc1b; pa.h0 = h0bf;
  prep_kernel<<<1249 + (N * 64) / 256, 256, 0, stream>>>(pa);

  // ---------------- CSR build ----------------
  hist_kernel<<<(E + 255) / 256, 256, 0, stream>>>(edst, cnt, E);
  scan_kernel<<<1, 256, 0, stream>>>(cnt, offs, cur, N);
  scatter_kernel<<<(E + 255) / 256, 256, 0, stream>>>(esrc, edst, cur, csr, E);

  // ---------------- GAT stack ----------------
  gemm(h0bf, g0Wt, nullptr, nullptr, hWb, N, DMODEL, 64, 0, stream, g0as, g0ad, ssrc, sdst);
  gat_fused_kernel<<<N / 4, 256, 0, stream>>>(hWb, offs, csr, ssrc, sdst, g0b, nullptr, P0);

  bf16* pin = P0; bf16* pout = P1;
  for (int i = 0; i < 3; i++) {
    gemm(pin, gWt + (size_t)i * 65536, nullptr, nullptr, hWb, N, DMODEL, DMODEL, 0, stream,
         gas + i * 256, gad + i * 256, ssrc, sdst);
    gat_fused_kernel<<<N / 4, 256, 0, stream>>>(hWb, offs, csr, ssrc, sdst, gb + i * DMODEL,
                                                (i == 2) ? A : nullptr, pout);
    bf16* tmp = pin; pin = pout; pout = tmp;
  }
  bf16* tbf = pin;  // t bf16; t f32 in A

  // ---------------- projections (cross KV, self QKV) + single V-transpose dispatch ----------------
  gemm(tbf, caWkT, kvb, nullptr, Bkv, N, 512, DMODEL, 0, stream);
  gemm(tbf, saWqT, qkvb, nullptr, Bqkv, N, 768, DMODEL, 0, stream);
  vtrans2_kernel<<<dim3(32, 8, 2 * NGRAPH), 256, 0, stream>>>(Bkv, Bqkv, VtC, VtS);

  // ---------------- self-attention ----------------
  attn_mfma_kernel<<<dim3(SQLEN / 64, 2, NGRAPH), 256, 0, stream>>>(
      Bqkv, 768, Bqkv + 256, 768, VtS, Batt);
  gemm(Batt, saWoT, sabo, Bb, nullptr, N, DMODEL, DMODEL, 0, stream);
  ln_kernel<<<N / 4, 256, 0, stream>>>(A, Bb, ln1g, ln1b, Kb, P0, nullptr);  // t1

  // ---------------- cross-attention ----------------
  gemm(P0, caWqT, cabq, nullptr, Bq, N, DMODEL, DMODEL, 0, stream);
  attn_mfma_kernel<<<dim3(SQLEN / 64, 2, NGRAPH), 256, 0, stream>>>(
      Bq, 256, Bkv, 512, VtC, Batt);
  gemm(Batt, caWoT, cabo, Bb, nullptr, N, DMODEL, DMODEL, 0, stream);
  ln_kernel<<<N / 4, 256, 0, stream>>>(Kb, Bb, ln2g, ln2b, A, P0, nullptr);  // t2

  // ---------------- feed-forward ----------------
  gemm(P0, ff1Wt, ff1b, nullptr, FFIb, N, 1024, DMODEL, 1, stream);  // relu
  gemm(FFIb, ff2Wt, ff2b, Bb, nullptr, N, DMODEL, 1024, 0, stream);
  ln_kernel<<<N / 4, 256, 0, stream>>>(A, Bb, ln3g, ln3b, A, nullptr, pooled);  // t3 + zero pooled

  // ---------------- pool + final FC ----------------
  pool_kernel<<<dim3(NGRAPH, 8), 256, 0, stream>>>(A, pooled);
  final_fc_kernel<<<dim3(4, NGRAPH), 256, 0, stream>>>(pooled, fcW, fcb, (float*)d_out);
}